// Round 4
// baseline (279.390 us; speedup 1.0000x reference)
//
#include <hip/hip_runtime.h>
#include <math.h>

// Problem constants (match reference)
#define MB 8      // batch
#define MM 384    // checks
#define NN 1536   // variables
#define LL 20     // layers
#define RW 8      // row weight of H
#define HE 4      // edges per thread (half row)
#define NE (MM*RW)  // 3072 edges
#define NT 768    // bp block size (2 threads per check row)

// ---------------------------------------------------------------------------
// Setup A: zero the per-row counters and the output scalar.
// ---------------------------------------------------------------------------
__global__ void zero_kernel(int* __restrict__ cnt, float* __restrict__ out) {
    int t = blockIdx.x * blockDim.x + threadIdx.x;
    if (t < MM) cnt[t] = 0;
    if (t == 0) out[0] = 0.0f;
}

// ---------------------------------------------------------------------------
// Setup B: order-free compaction of H's nonzero columns (1 thread / element).
// Column order within a row only permutes fp rounding order downstream.
// ---------------------------------------------------------------------------
__global__ __launch_bounds__(256) void compact_kernel(
    const float* __restrict__ H,
    int* __restrict__ cnt,
    int* __restrict__ col_idx) {
    int idx = blockIdx.x * 256 + threadIdx.x;
    if (idx >= MM * NN) return;
    if (H[idx] != 0.0f) {
        int m = idx / NN;
        int c = idx - m * NN;
        int pos = atomicAdd(&cnt[m], 1);
        if (pos < RW) col_idx[m * RW + pos] = c;
    }
}

// ---------------------------------------------------------------------------
// Main BP kernel: one block per batch element, 768 threads = 2 per check row
// (4 edges each). ONE barrier per layer. Per-layer weights are gathered
// DIRECTLY from w_llr / w_de with a one-layer-ahead register prefetch.
//   - S: 3-buffer rotation (read S[l%3], scatter S[(l+1)%3] fused with next
//     layer's w_de — w_de[0] never needed since msg_0 = 0 — reset S[(l+2)%3]).
//   - beliefs: 2-buffer ping-pong, loss deferred one layer.
//   - cross-half product combine via __shfl_xor (partner = adjacent lane).
// ---------------------------------------------------------------------------
__global__ __launch_bounds__(NT) void bp_kernel(
    const float* __restrict__ synd,       // (B,M,1)
    const float* __restrict__ errors,     // (B,N)
    const float* __restrict__ llrs,       // (N)
    const float* __restrict__ marg_llr,   // (N)
    const float* __restrict__ res_w,      // (L)
    const float* __restrict__ rhos,       // (L)
    const int*   __restrict__ col_idx,    // (E)
    const float* __restrict__ marg_de,    // (M,N)
    const float* __restrict__ w_llr,      // (L,N)
    const float* __restrict__ w_de,       // (L,M,N)
    float* __restrict__ out) {

    __shared__ float s_S[3][NN];
    __shared__ float s_bel[2][NN];
    __shared__ float s_rw[LL];
    __shared__ float s_rho[LL];
    __shared__ float s_red[12];

    const int b = blockIdx.x;
    const int t = threadIdx.x;
    const int m = t >> 1;        // check row
    // edges owned: m*RW + (t&1)*HE + k, k=0..3

    // ---- per-thread register state ----
    int col[HE];
    {
        const int4 ci = ((const int4*)col_idx)[t];   // 16B coalesced
        col[0] = ci.x; col[1] = ci.y; col[2] = ci.z; col[3] = ci.w;
    }
    float msg[HE] = {0.0f, 0.0f, 0.0f, 0.0f};
    float marg[HE], llr_c[HE];
    #pragma unroll
    for (int k = 0; k < HE; ++k) {
        marg[k]  = marg_de[m * NN + col[k]];
        llr_c[k] = llrs[col[k]];
    }
    const float sgn = 1.0f - 2.0f * synd[b * MM + m];

    float bias[2], omeg[2];
    #pragma unroll
    for (int i = 0; i < 2; ++i) {
        int n = t + i * NT;
        bias[i] = llrs[n] * marg_llr[n];
        omeg[i] = 1.0f - errors[b * NN + n];
        s_S[0][n] = 0.0f; s_S[1][n] = 0.0f; s_S[2][n] = 0.0f;
        s_bel[0][n] = bias[i]; s_bel[1][n] = bias[i];
    }
    if (t < LL) { s_rw[t] = res_w[t]; s_rho[t] = rhos[t]; }

    // ---- prefetch layer-0 w_llr and layer-1 w_de into registers ----
    float wl_c[HE], wS[HE], wl_n[HE], wS_n[HE];
    #pragma unroll
    for (int k = 0; k < HE; ++k) {
        wl_c[k] = w_llr[col[k]];                                   // l=0
        wS[k]   = w_de[(size_t)MM * NN + (size_t)m * NN + col[k]]; // l=1
    }

    float loss = 0.0f;
    __syncthreads();

    for (int l = 0; l < LL; ++l) {
        // prefetch w_llr[l+1] and w_de[l+2] (consumed next layer)
        {
            int lb = (l + 1 < LL) ? (l + 1) : (LL - 1);
            int lw = (l + 2 < LL) ? (l + 2) : (LL - 1);
            const float* wlp = w_llr + lb * NN;
            const float* wdp = w_de + (size_t)lw * MM * NN + (size_t)m * NN;
            #pragma unroll
            for (int k = 0; k < HE; ++k) {
                wl_n[k] = wlp[col[k]];
                wS_n[k] = wdp[col[k]];
            }
        }

        // deferred loss for layer l-1 (independent of this layer's chain)
        if (l > 0) {
            const float rr = s_rho[l - 1];
            const int   pb = (l - 1) & 1;
            float acc = 0.0f;
            #pragma unroll
            for (int i = 0; i < 2; ++i) {
                int n = t + i * NT;
                float be = s_bel[pb][n];
                float sp = fmaxf(be, 0.0f) + __logf(1.0f + __expf(-fabsf(be)));
                acc += sp - omeg[i] * be;
                s_bel[pb][n] = bias[i];   // reset for reuse at layer l+1
            }
            loss += rr * acc;
        }

        // reset the idle S buffer (owned slots; consumed two layers ago)
        {
            const int sb = (l + 2) % 3;
            s_S[sb][t] = 0.0f;
            s_S[sb][t + NT] = 0.0f;
        }

        const float rw_ = s_rw[l];
        const int cs = l % 3, ns = (l + 1) % 3, bb = l & 1;

        // check-node update over this thread's 4 edges
        float d[HE];
        #pragma unroll
        for (int k = 0; k < HE; ++k) {
            float te = llr_c[k] * wl_c[k] + s_S[cs][col[k]] - msg[k];
            float e  = __expf(te);                          // v_exp_f32
            float dd = 1.0f - 2.0f * __builtin_amdgcn_rcpf(e + 1.0f);
            dd = fminf(fmaxf(dd, -1.0f), 1.0f);             // guard rcp rounding
            if (dd == 0.0f) dd = 1.0f;                      // jnp.where(d==0,1,d)
            d[k] = dd;
        }
        float p01 = d[0] * d[1], p23 = d[2] * d[3];
        float p4  = p01 * p23;
        float pot = __shfl_xor(p4, 1, 64);                  // partner half's product
        float ex[HE];
        ex[0] = d[1] * p23; ex[1] = d[0] * p23;
        ex[2] = p01 * d[3]; ex[3] = p01 * d[2];

        #pragma unroll
        for (int k = 0; k < HE; ++k) {
            float x  = ex[k] * pot;
            float r  = (1.0f + x) * __builtin_amdgcn_rcpf(1.0f - x);
            float nm = sgn * __logf(r) + rw_ * msg[k];      // 2*atanh(x)*sgn + res*msg
            msg[k] = nm;
            atomicAdd(&s_S[ns][col[k]], nm * wS[k]);        // next layer's var-node sum
            atomicAdd(&s_bel[bb][col[k]], nm * marg[k]);    // beliefs
        }

        // rotate prefetched weights
        #pragma unroll
        for (int k = 0; k < HE; ++k) { wl_c[k] = wl_n[k]; wS[k] = wS_n[k]; }

        __syncthreads();   // the ONE barrier per layer
    }

    // tail: loss for the last layer
    {
        const float rr = s_rho[LL - 1];
        const int   pb = (LL - 1) & 1;
        float acc = 0.0f;
        #pragma unroll
        for (int i = 0; i < 2; ++i) {
            int n = t + i * NT;
            float be = s_bel[pb][n];
            float sp = fmaxf(be, 0.0f) + __logf(1.0f + __expf(-fabsf(be)));
            acc += sp - omeg[i] * be;
        }
        loss += rr * acc;
    }

    // ---- block-wide loss reduction (12 waves) ----
    #pragma unroll
    for (int off = 32; off > 0; off >>= 1)
        loss += __shfl_down(loss, off, 64);
    int wave = t >> 6, lane = t & 63;
    if (lane == 0) s_red[wave] = loss;
    __syncthreads();
    if (t == 0) {
        float tot = 0.0f;
        #pragma unroll
        for (int w = 0; w < 12; ++w) tot += s_red[w];
        atomicAdd(out, tot * (1.0f / (float)MB));
    }
}

// ---------------------------------------------------------------------------
extern "C" void kernel_launch(void* const* d_in, const int* in_sizes, int n_in,
                              void* d_out, int out_size, void* d_ws, size_t ws_size,
                              hipStream_t stream) {
    const float* synd     = (const float*)d_in[0];  // (B,M,1)
    const float* errors   = (const float*)d_in[1];  // (B,N)
    const float* H        = (const float*)d_in[2];  // (M,N)
    const float* llrs     = (const float*)d_in[3];  // (N)
    const float* w_de     = (const float*)d_in[4];  // (L,M,N)
    const float* w_llr    = (const float*)d_in[5];  // (L,N)
    const float* marg_de  = (const float*)d_in[6];  // (M,N)
    const float* marg_llr = (const float*)d_in[7];  // (N)
    const float* res_w    = (const float*)d_in[8];  // (L)
    const float* rhos     = (const float*)d_in[9];  // (L)
    float* out = (float*)d_out;

    // Workspace: cnt[MM], then col_idx[NE] (16B-aligned: 384*4 = 1536 B offset)
    int* cnt     = (int*)d_ws;
    int* col_idx = (int*)d_ws + MM;

    zero_kernel<<<2, 256, 0, stream>>>(cnt, out);
    compact_kernel<<<(MM * NN + 255) / 256, 256, 0, stream>>>(H, cnt, col_idx);
    bp_kernel<<<MB, NT, 0, stream>>>(synd, errors, llrs, marg_llr, res_w, rhos,
                                     col_idx, marg_de, w_llr, w_de, out);
}

// Round 5
// 271.532 us; speedup vs baseline: 1.0289x; 1.0289x over previous
//
#include <hip/hip_runtime.h>
#include <math.h>

// Problem constants (match reference)
#define MB 8      // batch
#define MM 384    // checks
#define NN 1536   // variables
#define LL 20     // layers
#define RW 8      // row weight of H
#define HE 4      // edges per thread (half row)
#define NE (MM*RW)  // 3072 edges
#define NT 768    // bp block size (2 threads per check row)

// ---------------------------------------------------------------------------
// Fused setup: one block (256 thr = 4 waves) per check row.
//  4-wave ballot scan of H row m -> RW column indices (order-preserving),
//  then gather all per-layer edge weights into contiguous ws arrays
//  (coalesced consumption in bp). Block 0 zeroes the output scalar.
// ---------------------------------------------------------------------------
__global__ __launch_bounds__(256) void setup_kernel(
    const float* __restrict__ H,
    const float* __restrict__ llrs,
    const float* __restrict__ w_llr,
    const float* __restrict__ w_de,
    const float* __restrict__ marg_de,
    int*   __restrict__ col_idx,
    float* __restrict__ marg_e,
    float* __restrict__ base_e,
    float* __restrict__ wde_e,
    float* __restrict__ out) {
    const int m = blockIdx.x;
    const int t = threadIdx.x;
    const int w = t >> 6, lane = t & 63;
    __shared__ int s_qcol[4][RW];
    __shared__ int s_qcnt[4];
    __shared__ int s_col[RW];

    const float* row = H + (size_t)m * NN;
    int count = 0;
    for (int c0 = w * 384; c0 < (w + 1) * 384; c0 += 64) {
        float v = row[c0 + lane];
        unsigned long long mask = __ballot(v != 0.0f);
        if (v != 0.0f) {
            int pos = count + (int)__popcll(mask & ((1ull << lane) - 1ull));
            if (pos < RW) s_qcol[w][pos] = c0 + lane;
        }
        count += (int)__popcll(mask);
    }
    if (lane == 0) s_qcnt[w] = (count < RW) ? count : RW;
    __syncthreads();
    if (t == 0) {
        int off = 0;
        for (int q = 0; q < 4; ++q)
            for (int i = 0; i < s_qcnt[q]; ++i) {
                if (off < RW) s_col[off] = s_qcol[q][i];
                ++off;
            }
    }
    __syncthreads();

    if (t < RW) {
        int c = s_col[t];
        col_idx[m * RW + t] = c;
        marg_e[m * RW + t]  = marg_de[m * NN + c];
    }
    if (m == 0 && t == 0) out[0] = 0.0f;

    // 20 layers x 8 edges = 160 gathers per row; 256 threads -> <=1 each
    for (int idx = t; idx < LL * RW; idx += 256) {
        int l = idx >> 3;
        int k = idx & 7;
        int c = s_col[k];
        base_e[l * NE + m * RW + k] = llrs[c] * w_llr[l * NN + c];
        wde_e [l * NE + m * RW + k] = w_de[(size_t)l * MM * NN + (size_t)m * NN + c];
    }
}

// ---------------------------------------------------------------------------
// Main BP kernel: one block per batch element, 768 threads = 2 per check row
// (4 edges each). ONE barrier per layer.
//   - LDS float accumulation uses unsafeAtomicAdd -> native ds_add_f32
//     (plain atomicAdd compiles to a CAS retry loop without
//     -munsafe-fp-atomics; that loop was the R1-R4 bottleneck theory).
//   - S: 3-buffer rotation (read S[l%3], scatter S[(l+1)%3] fused with next
//     layer's w_de — w_de[0] never needed since msg_0 = 0 — reset S[(l+2)%3]).
//   - beliefs: 2-buffer ping-pong, loss deferred one layer.
//   - per-edge weights: coalesced float4 loads from pre-gathered ws arrays,
//     prefetched one layer ahead into registers.
// ---------------------------------------------------------------------------
__global__ __launch_bounds__(NT) void bp_kernel(
    const float* __restrict__ synd,       // (B,M,1)
    const float* __restrict__ errors,     // (B,N)
    const float* __restrict__ llrs,       // (N)
    const float* __restrict__ marg_llr,   // (N)
    const float* __restrict__ res_w,      // (L)
    const float* __restrict__ rhos,       // (L)
    const int*   __restrict__ col_idx,    // (E)
    const float* __restrict__ marg_e_g,   // (E)
    const float* __restrict__ base_e_g,   // (L,E)
    const float* __restrict__ wde_e_g,    // (L,E)
    float* __restrict__ out) {

    __shared__ float s_S[3][NN];
    __shared__ float s_bel[2][NN];
    __shared__ float s_rw[LL];
    __shared__ float s_rho[LL];
    __shared__ float s_red[12];

    const int b = blockIdx.x;
    const int t = threadIdx.x;
    const int m = t >> 1;        // check row; edges owned: t*HE + k

    // ---- per-thread register state ----
    int col[HE];
    {
        const int4 ci = ((const int4*)col_idx)[t];   // 16B coalesced
        col[0] = ci.x; col[1] = ci.y; col[2] = ci.z; col[3] = ci.w;
    }
    float msg[HE] = {0.0f, 0.0f, 0.0f, 0.0f};
    float marg[HE];
    {
        const float4 mg = ((const float4*)marg_e_g)[t];
        marg[0] = mg.x; marg[1] = mg.y; marg[2] = mg.z; marg[3] = mg.w;
    }
    const float sgn = 1.0f - 2.0f * synd[b * MM + m];

    float bias[2], omeg[2];
    #pragma unroll
    for (int i = 0; i < 2; ++i) {
        int n = t + i * NT;
        bias[i] = llrs[n] * marg_llr[n];
        omeg[i] = 1.0f - errors[b * NN + n];
        s_S[0][n] = 0.0f; s_S[1][n] = 0.0f; s_S[2][n] = 0.0f;
        s_bel[0][n] = bias[i]; s_bel[1][n] = bias[i];
    }
    if (t < LL) { s_rw[t] = res_w[t]; s_rho[t] = rhos[t]; }

    // ---- prefetch: bc = base_e[layer 0], wS = wde_e[layer 1] ----
    float bc[HE], wS[HE], bn[HE], wn2[HE];
    {
        const float4 bp4 = ((const float4*)(base_e_g))[t];
        bc[0] = bp4.x; bc[1] = bp4.y; bc[2] = bp4.z; bc[3] = bp4.w;
        const float4 wp4 = ((const float4*)(wde_e_g + 1 * NE))[t];
        wS[0] = wp4.x; wS[1] = wp4.y; wS[2] = wp4.z; wS[3] = wp4.w;
    }

    float loss = 0.0f;
    __syncthreads();

    for (int l = 0; l < LL; ++l) {
        // prefetch base_e[l+1] and wde_e[l+2] (consumed next layer)
        {
            int lb = (l + 1 < LL) ? (l + 1) : (LL - 1);
            int lw = (l + 2 < LL) ? (l + 2) : (LL - 1);
            const float4 bp4 = ((const float4*)(base_e_g + lb * NE))[t];
            bn[0]  = bp4.x; bn[1]  = bp4.y; bn[2]  = bp4.z; bn[3]  = bp4.w;
            const float4 wp4 = ((const float4*)(wde_e_g + lw * NE))[t];
            wn2[0] = wp4.x; wn2[1] = wp4.y; wn2[2] = wp4.z; wn2[3] = wp4.w;
        }

        // deferred loss for layer l-1 (independent of this layer's chain)
        if (l > 0) {
            const float rr = s_rho[l - 1];
            const int   pb = (l - 1) & 1;
            float acc = 0.0f;
            #pragma unroll
            for (int i = 0; i < 2; ++i) {
                int n = t + i * NT;
                float be = s_bel[pb][n];
                float sp = fmaxf(be, 0.0f) + __logf(1.0f + __expf(-fabsf(be)));
                acc += sp - omeg[i] * be;
                s_bel[pb][n] = bias[i];   // reset for reuse at layer l+1
            }
            loss += rr * acc;
        }

        // reset the idle S buffer (owned slots; consumed two layers ago)
        {
            const int sb = (l + 2) % 3;
            s_S[sb][t] = 0.0f;
            s_S[sb][t + NT] = 0.0f;
        }

        const float rw_ = s_rw[l];
        const int cs = l % 3, ns = (l + 1) % 3, bb = l & 1;

        // check-node update over this thread's 4 edges
        float d[HE];
        #pragma unroll
        for (int k = 0; k < HE; ++k) {
            float te = bc[k] + s_S[cs][col[k]] - msg[k];
            float e  = __expf(te);                          // v_exp_f32
            float dd = 1.0f - 2.0f * __builtin_amdgcn_rcpf(e + 1.0f);
            dd = fminf(fmaxf(dd, -1.0f), 1.0f);             // guard rcp rounding
            if (dd == 0.0f) dd = 1.0f;                      // jnp.where(d==0,1,d)
            d[k] = dd;
        }
        float p01 = d[0] * d[1], p23 = d[2] * d[3];
        float p4  = p01 * p23;
        float pot = __shfl_xor(p4, 1, 64);                  // partner half's product
        float ex[HE];
        ex[0] = d[1] * p23; ex[1] = d[0] * p23;
        ex[2] = p01 * d[3]; ex[3] = p01 * d[2];

        #pragma unroll
        for (int k = 0; k < HE; ++k) {
            float x  = ex[k] * pot;
            float r  = (1.0f + x) * __builtin_amdgcn_rcpf(1.0f - x);
            float nm = sgn * __logf(r) + rw_ * msg[k];      // 2*atanh(x)*sgn + res*msg
            msg[k] = nm;
            unsafeAtomicAdd(&s_S[ns][col[k]], nm * wS[k]);  // ds_add_f32, no CAS loop
            unsafeAtomicAdd(&s_bel[bb][col[k]], nm * marg[k]);
        }

        // rotate prefetched weights
        #pragma unroll
        for (int k = 0; k < HE; ++k) { bc[k] = bn[k]; wS[k] = wn2[k]; }

        __syncthreads();   // the ONE barrier per layer
    }

    // tail: loss for the last layer
    {
        const float rr = s_rho[LL - 1];
        const int   pb = (LL - 1) & 1;
        float acc = 0.0f;
        #pragma unroll
        for (int i = 0; i < 2; ++i) {
            int n = t + i * NT;
            float be = s_bel[pb][n];
            float sp = fmaxf(be, 0.0f) + __logf(1.0f + __expf(-fabsf(be)));
            acc += sp - omeg[i] * be;
        }
        loss += rr * acc;
    }

    // ---- block-wide loss reduction (12 waves) ----
    #pragma unroll
    for (int off = 32; off > 0; off >>= 1)
        loss += __shfl_down(loss, off, 64);
    int wave = t >> 6, lane = t & 63;
    if (lane == 0) s_red[wave] = loss;
    __syncthreads();
    if (t == 0) {
        float tot = 0.0f;
        #pragma unroll
        for (int w = 0; w < 12; ++w) tot += s_red[w];
        atomicAdd(out, tot * (1.0f / (float)MB));
    }
}

// ---------------------------------------------------------------------------
extern "C" void kernel_launch(void* const* d_in, const int* in_sizes, int n_in,
                              void* d_out, int out_size, void* d_ws, size_t ws_size,
                              hipStream_t stream) {
    const float* synd     = (const float*)d_in[0];  // (B,M,1)
    const float* errors   = (const float*)d_in[1];  // (B,N)
    const float* H        = (const float*)d_in[2];  // (M,N)
    const float* llrs     = (const float*)d_in[3];  // (N)
    const float* w_de     = (const float*)d_in[4];  // (L,M,N)
    const float* w_llr    = (const float*)d_in[5];  // (L,N)
    const float* marg_de  = (const float*)d_in[6];  // (M,N)
    const float* marg_llr = (const float*)d_in[7];  // (N)
    const float* res_w    = (const float*)d_in[8];  // (L)
    const float* rhos     = (const float*)d_in[9];  // (L)
    float* out = (float*)d_out;

    // Workspace layout (4-byte elements, 16B-aligned partitions)
    int*   col_idx = (int*)d_ws;            // NE ints
    float* marg_e  = (float*)d_ws + NE;     // NE floats
    float* base_e  = marg_e + NE;           // L*NE floats
    float* wde_e   = base_e + LL * NE;      // L*NE floats

    setup_kernel<<<MM, 256, 0, stream>>>(H, llrs, w_llr, w_de, marg_de,
                                         col_idx, marg_e, base_e, wde_e, out);
    bp_kernel<<<MB, NT, 0, stream>>>(synd, errors, llrs, marg_llr, res_w, rhos,
                                     col_idx, marg_e, base_e, wde_e, out);
}